// Round 7
// baseline (344.099 us; speedup 1.0000x reference)
//
#include <hip/hip_runtime.h>

#define NN 4096
#define NC 10
#define NW 64            // u64 words per adjacency row
#define CHW 16           // words per staged chunk
#define NCHUNK 4         // NW / CHW
#define BH 16            // band height: tile = 16x16 pairs, 32 rows staged
typedef unsigned long long u64;

#define S1F 0.73105857863000489f   // sigmoid(1.0)

// ---------------- kernel 1: pack adjacency rows + zero accumulators --------
__global__ __launch_bounds__(256) void pack_bits_kernel(
    const int* __restrict__ adj, u64* __restrict__ bits, int* __restrict__ deg,
    int* __restrict__ accz) {
  if (blockIdx.x == 0) {                 // zero the 1536B accumulator strip
    for (int i = threadIdx.x; i < 384; i += 256) accz[i] = 0;
  }
  int p = blockIdx.x;
  int tid = threadIdx.x;
  int wv = tid >> 6, lane = tid & 63;
  const int* row = adj + (size_t)p * NN;
  int cnt = 0;
  for (int w = wv; w < NW; w += 4) {
    int a = row[(w << 6) + lane];
    u64 b = __ballot(a != 0);
    if (lane == 0) bits[(size_t)p * NW + w] = b;
    cnt += (a != 0) ? 1 : 0;
  }
  __shared__ int red[256];
  red[tid] = cnt;
  __syncthreads();
  for (int s = 128; s > 0; s >>= 1) {
    if (tid < s) red[tid] += red[tid + s];
    __syncthreads();
  }
  if (tid == 0) deg[p] = red[0];
}

// ---------------- kernel 2: per-node CE + pos + per-class masked counts ----
__global__ __launch_bounds__(256) void node_kernel(
    const float* __restrict__ preds, const int* __restrict__ labels,
    const int* __restrict__ mask, float* __restrict__ pos,
    int* __restrict__ Ncnt, float* __restrict__ ceAcc) {
  int n = blockIdx.x * blockDim.x + threadIdx.x;
  float ce = 0.f;
  if (n < NN) {
    int l = labels[n];
    float r[NC];
    float mx = -1e30f, rl = 0.f;
#pragma unroll
    for (int c = 0; c < NC; c++) {
      float v = preds[n * NC + c];
      r[c] = v;
      if (c == l) rl = v;
      mx = fmaxf(mx, v);
    }
    float s = 0.f;
#pragma unroll
    for (int c = 0; c < NC; c++) s += expf(r[c] - mx);
    float lse = mx + logf(s);
    pos[n] = rl;
    ce = lse - rl;
    if (mask[n] != 0) atomicAdd(&Ncnt[l], 1);
  }
  __shared__ float red[256];
  red[threadIdx.x] = ce;
  __syncthreads();
  for (int s = 128; s > 0; s >>= 1) {
    if (threadIdx.x < s) red[threadIdx.x] += red[threadIdx.x + s];
    __syncthreads();
  }
  if (threadIdx.x == 0) atomicAdd(ceAcc, red[0]);
}

// ---------------- kernel 3: deterministic mask compaction (1 block) --------
__global__ __launch_bounds__(256) void compact_kernel(
    const int* __restrict__ mask, int* __restrict__ list, int* __restrict__ Mcount) {
  __shared__ int cnt[256];
  int tid = threadIdx.x;
  int base = tid * 16;
  int c = 0;
  for (int i = 0; i < 16; i++) c += (mask[base + i] != 0) ? 1 : 0;
  cnt[tid] = c;
  __syncthreads();
  for (int s = 1; s < 256; s <<= 1) {
    int v = (tid >= s) ? cnt[tid - s] : 0;
    __syncthreads();
    cnt[tid] += v;
    __syncthreads();
  }
  int off = cnt[tid] - c;
  for (int i = 0; i < 16; i++) {
    int idx = base + i;
    if (mask[idx] != 0) list[off++] = idx;
  }
  if (tid == 255) *Mcount = cnt[255];
}

// ---------------- kernel 4: wave-autonomous 16x16 pair tiles ---------------
// 8256 wave-tiles at M=2048 -> 8 waves/SIMD of available work (the R6
// limiter was work availability: 32x32 tiles gave only 2 waves/SIMD).
// Per-wave LDS slice 4 KB (32 rows x 16 words), no __syncthreads in the
// main loop. Swizzle key (row>>1)&7 makes all ds_read_b128 conflict-free.
// Epilogue scatter loads issue at use; cross-wave occupancy hides them.
// Last block (atomic ticket) performs the final gate+reduce.
__global__ __launch_bounds__(256, 4) void pair_kernel(
    const u64* __restrict__ bits, const int* __restrict__ deg,
    const float* __restrict__ pos, const float* __restrict__ preds,
    const int* __restrict__ labels, const int* __restrict__ list,
    const int* __restrict__ Mcount, const int* __restrict__ Ncnt,
    const float* __restrict__ ceAcc,
    float* __restrict__ gT, int* __restrict__ gS, int* __restrict__ gI,
    int* __restrict__ ticket, float* __restrict__ out) {
  __shared__ __align__(16) u64 TB[4][32][CHW];   // 16 KB: 4 waves x 32 rows
  __shared__ float binT[100];
  __shared__ int fS[100], fI[100];
  __shared__ float red[256];
  __shared__ int lastFlag;

  int tid = threadIdx.x;
  int wv = tid >> 6, lane = tid & 63;
  for (int b = tid; b < 100; b += 256) { binT[b] = 0.f; fS[b] = 0; fI[b] = 0; }
  __syncthreads();                                // bins ready

  int M = *Mcount;
  int ntp = (M + BH - 1) / BH;
  int ntiles = (ntp * (ntp + 1)) >> 1;
  int gw = blockIdx.x * 4 + wv;
  int nw = gridDim.x * 4;

  int lp = lane >> 3, lq = lane & 7;              // 8x8 lane grid, 2x2 pairs
  int sr = lane >> 1, sh = lane & 1;              // staging row (0..31), half
  int srh = (sr >> 1) & 7;                        // swizzle key
  u64 (*tb)[CHW] = TB[wv];

  for (int t = gw; t < ntiles; t += nw) {
    // band decode: first index of band k = k*ntp - k(k-1)/2
    float af = (float)(2 * ntp + 1);
    int tp = (int)((af - sqrtf(af * af - 8.0f * (float)t)) * 0.5f);
    while ((tp + 1) * ntp - (((tp + 1) * tp) >> 1) <= t) tp++;
    while (tp * ntp - ((tp * (tp - 1)) >> 1) > t) tp--;
    int tq = tp + (t - (tp * ntp - ((tp * (tp - 1)) >> 1)));
    bool diag = (tp == tq);

    // my staged row's node (rows 0-15 = P band, 16-31 = Q band)
    int smi = (sr < BH) ? (tp * BH + sr) : (tq * BH + (sr - BH));
    int snd = (smi < M) ? list[smi] : -1;
    const u64* rowp = bits + (size_t)((snd >= 0) ? snd : 0) * NW;
    bool live = (snd >= 0);

    // chunk-0 staging loads (issued first, needed soonest)
    ulonglong2 pf[4];
    const u64* src0 = rowp + (sh << 3);
#pragma unroll
    for (int x = 0; x < 4; x++)
      pf[x] = live ? *(const ulonglong2*)(src0 + (x << 1))
                   : make_ulonglong2(0ULL, 0ULL);

    // epilogue metadata for my 2 P rows + 2 Q rows (in flight under popc)
    int pgs[2], lis[2], dgp[2], sfp[2]; float pps[2];
    int qgs[2], ljs[2], dgq[2], sfq[2]; float pqs[2];
#pragma unroll
    for (int i = 0; i < 2; i++) {
      int mi = tp * BH + (lp << 1) + i;
      int nd = (mi < M) ? list[mi] : -1;
      pgs[i] = nd;
      lis[i] = (nd >= 0) ? labels[nd] : 0;
      dgp[i] = (nd >= 0) ? deg[nd] : 0;
      pps[i] = (nd >= 0) ? pos[nd] : 0.f;
      sfp[i] = (nd >= 0) ? (int)((bits[(size_t)nd * NW + (nd >> 6)] >> (nd & 63)) & 1ULL) : 0;
    }
#pragma unroll
    for (int j = 0; j < 2; j++) {
      int mi = tq * BH + (lq << 1) + j;
      int nd = (mi < M) ? list[mi] : -1;
      qgs[j] = nd;
      ljs[j] = (nd >= 0) ? labels[nd] : 0;
      dgq[j] = (nd >= 0) ? deg[nd] : 0;
      pqs[j] = (nd >= 0) ? pos[nd] : 0.f;
      sfq[j] = (nd >= 0) ? (int)((bits[(size_t)nd * NW + (nd >> 6)] >> (nd & 63)) & 1ULL) : 0;
    }

    int acc[2][2] = {{0, 0}, {0, 0}};

    for (int c = 0; c < NCHUNK; c++) {
      // write staged regs to swizzled 16B slots of this wave's LDS slice
#pragma unroll
      for (int x = 0; x < 4; x++)
        *(ulonglong2*)&tb[sr][(((sh << 2) + x) ^ srh) << 1] = pf[x];
      if (c < NCHUNK - 1) {
        const u64* src = rowp + ((c + 1) * CHW) + (sh << 3);
#pragma unroll
        for (int x = 0; x < 4; x++)
          pf[x] = live ? *(const ulonglong2*)(src + (x << 1))
                       : make_ulonglong2(0ULL, 0ULL);
      }
      // wave-synchronous: drain DS writes before reads (no barrier)
      asm volatile("s_waitcnt lgkmcnt(0)" ::: "memory");

#pragma unroll
      for (int y = 0; y < 8; y++) {               // 8 word-pairs per chunk
        ulonglong2 RP[2], RQ[2];
#pragma unroll
        for (int i = 0; i < 2; i++)
          RP[i] = *(ulonglong2*)&tb[(lp << 1) + i][(y ^ lp) << 1];
#pragma unroll
        for (int j = 0; j < 2; j++)
          RQ[j] = *(ulonglong2*)&tb[BH + (lq << 1) + j][(y ^ lq) << 1];
#pragma unroll
        for (int i = 0; i < 2; i++)
#pragma unroll
          for (int j = 0; j < 2; j++)
            acc[i][j] += (int)__popcll(RP[i].x & RQ[j].x)
                       + (int)__popcll(RP[i].y & RQ[j].y);
      }
    }

    // epilogue: both orientations per unordered pair
#pragma unroll
    for (int i = 0; i < 2; i++) {
      if (pgs[i] < 0) continue;
      int pl = (lp << 1) + i;
      int li = lis[i];
      int pg = pgs[i];
#pragma unroll
      for (int j = 0; j < 2; j++) {
        if (qgs[j] < 0) continue;
        int lj = ljs[j];
        if (li == lj) continue;                   // only off-diag bins matter
        int qr = (lq << 1) + j;
        if (diag && pl >= qr) continue;           // unordered once on diag
        int qg = qgs[j];
        int inter = acc[i][j];
        u64 rwp = bits[(size_t)pg * NW + (qg >> 6)];
        u64 rwq = bits[(size_t)qg * NW + (pg >> 6)];
        int apq = (int)((rwp >> (qg & 63)) & 1ULL);
        int aqp = (int)((rwq >> (pg & 63)) & 1ULL);
        int sub_f = dgp[i] - inter - (apq & (sfq[j] ^ 1));
        int sub_r = dgq[j] - inter - (aqp & (sfp[i] ^ 1));
        float rden = 1.f / (1.f + S1F * (float)inter);
        float xf = (1.f + S1F * (float)sub_f) * rden;
        float xr = (1.f + S1F * (float)sub_r) * rden;
        float Ef = __expf(preds[qg * NC + li] - pps[i]);
        float Er = __expf(preds[pg * NC + lj] - pqs[j]);
        float vf = 1.f / (1.f + __expf(xf));      // 1 - sigmoid(x)
        float vr = 1.f / (1.f + __expf(xr));
        atomicAdd(&binT[li * NC + lj], Ef * vf);
        atomicAdd(&binT[lj * NC + li], Er * vr);
        if (sub_f > 0) fS[li * NC + lj] = 1;      // same-value stores: safe
        if (sub_r > 0) fS[lj * NC + li] = 1;
        if (inter > 0) { fI[li * NC + lj] = 1; fI[lj * NC + li] = 1; }
      }
    }
  }

  __syncthreads();                                // all waves done
  for (int b = tid; b < 100; b += 256) {
    float v = binT[b];
    if (v != 0.f) atomicAdd(&gT[b], v);
    if (fS[b]) atomicOr(&gS[b], 1);
    if (fI[b]) atomicOr(&gI[b], 1);
  }
  __threadfence();
  if (tid == 0) {
    int old = atomicAdd(ticket, 1);
    lastFlag = (old == (int)gridDim.x - 1) ? 1 : 0;
  }
  __syncthreads();
  if (lastFlag) {                                 // last block: finalize
    float val = 0.f;
    if (tid < 100) {
      int i = tid / NC, j = tid - (tid / NC) * NC;
      float tv = atomicAdd(&gT[tid], 0.0f);       // device-scope coherent reads
      int sv = atomicOr(&gS[tid], 0);
      int iv = atomicOr(&gI[tid], 0);
      if (i != j && sv != 0 && iv != 0) {
        float Ni = fmaxf((float)Ncnt[i], 1.f);
        float Nj = fmaxf((float)Ncnt[j], 1.f);
        val = tv / (Ni * Nj);
      }
    }
    red[tid] = val;
    __syncthreads();
    for (int s = 128; s > 0; s >>= 1) {
      if (tid < s) red[tid] += red[tid + s];
      __syncthreads();
    }
    if (tid == 0) out[0] = ceAcc[0] / (float)NN + 0.001f * red[0];
  }
}

// ---------------- launch ---------------------------------------------------
extern "C" void kernel_launch(void* const* d_in, const int* in_sizes, int n_in,
                              void* d_out, int out_size, void* d_ws, size_t ws_size,
                              hipStream_t stream) {
  const float* preds  = (const float*)d_in[0];
  const int*   labels = (const int*)d_in[1];
  const int*   mask   = (const int*)d_in[2];
  const int*   adj    = (const int*)d_in[3];

  char* ws = (char*)d_ws;
  u64*   bits  = (u64*)(ws + 0);
  int*   deg   = (int*)(ws + 2097152);
  float* pos   = (float*)(ws + 2113536);
  int*   list  = (int*)(ws + 2129920);
  char*  accb  = ws + 2146304;           // 1536 B, zeroed by pack_bits blk 0
  float* ceAcc = (float*)(accb + 0);
  int*   Mcnt  = (int*)(accb + 8);
  int*   ticket= (int*)(accb + 12);
  int*   Ncnt  = (int*)(accb + 16);      // 10 ints
  float* gT    = (float*)(accb + 64);    // 100 floats
  int*   gS    = (int*)(accb + 512);     // 100 ints (flags)
  int*   gI    = (int*)(accb + 1024);    // 100 ints (flags)

  hipLaunchKernelGGL(pack_bits_kernel, dim3(NN), dim3(256), 0, stream,
                     adj, bits, deg, (int*)accb);
  hipLaunchKernelGGL(node_kernel, dim3(NN / 256), dim3(256), 0, stream,
                     preds, labels, mask, pos, Ncnt, ceAcc);
  hipLaunchKernelGGL(compact_kernel, dim3(1), dim3(256), 0, stream, mask, list, Mcnt);
  // M=2048 -> ntp=128 bands -> 8256 wave-tiles; 2064 blocks x 4 waves = 8256
  // waves (1 tile/wave); grid-stride covers other M.
  hipLaunchKernelGGL(pair_kernel, dim3(2064), dim3(256), 0, stream,
                     bits, deg, pos, preds, labels, list, Mcnt, Ncnt, ceAcc,
                     gT, gS, gI, ticket, (float*)d_out);
}

// Round 8
// 103.872 us; speedup vs baseline: 3.3127x; 3.3127x over previous
//
#include <hip/hip_runtime.h>

#define NN 4096
#define NC 10
#define NW 64            // u64 words per adjacency row
#define CHW 16           // words per staged chunk
#define NCHUNK 4         // NW / CHW
#define BH 32            // band height: tile = 32x32 pairs, 64 rows staged
typedef unsigned long long u64;
typedef long long s64;

#define S1F 0.73105857863000489f   // sigmoid(1.0)

// ws layout (bytes)
#define OFF_BITS   0           // 4096*64*8 = 2097152
#define OFF_DEG    2097152     // int[4096]
#define OFF_POS    2113536     // float[4096]
#define OFF_LIST   2129920     // int[4096]
#define OFF_ACC    2146304     // 1536 B strip (memset 0 each call)
#define OFF_CNT    2147840     // int[10][4096] = 163840
// acc strip offsets
#define A_CE    0
#define A_LOSS  4
#define A_MCNT  8
#define A_NCNT  16    // 10 ints
#define A_GD    64    // 10 ints
#define A_GE    128   // 100 ints
#define A_GSI   528   // 100 long long

// ---- kernel 1: pack adjacency bits + degrees + class-count table ---------
__global__ __launch_bounds__(256) void pack_bits_kernel(
    const int* __restrict__ adj, u64* __restrict__ bits, int* __restrict__ deg,
    int* __restrict__ cnt, const int* __restrict__ labels,
    const int* __restrict__ mask) {
  int p = blockIdx.x;
  int tid = threadIdx.x;
  int wv = tid >> 6, lane = tid & 63;
  const int* row = adj + (size_t)p * NN;
  int lb = labels[p];
  int mp = mask[p];
  int c = 0;
  for (int w = wv; w < NW; w += 4) {
    int a = row[(w << 6) + lane];
    u64 b = __ballot(a != 0);
    if (lane == 0) bits[(size_t)p * NW + w] = b;
    c += (a != 0) ? 1 : 0;
    if (mp && a != 0) atomicAdd(&cnt[lb * NN + (w << 6) + lane], 1);
  }
  __shared__ int red[256];
  red[tid] = c;
  __syncthreads();
  for (int s = 128; s > 0; s >>= 1) {
    if (tid < s) red[tid] += red[tid + s];
    __syncthreads();
  }
  if (tid == 0) deg[p] = red[0];
}

// ---- kernel 2: node CE/pos/Ncnt (blocks 0-15) + mask compaction (blk 16) --
__global__ __launch_bounds__(256) void node_compact_kernel(
    const float* __restrict__ preds, const int* __restrict__ labels,
    const int* __restrict__ mask, float* __restrict__ pos,
    int* __restrict__ Ncnt, float* __restrict__ ceAcc,
    int* __restrict__ list, int* __restrict__ Mcount) {
  int tid = threadIdx.x;
  if (blockIdx.x == 16) {                      // deterministic compaction
    __shared__ int cnt[256];
    int base = tid * 16;
    int c = 0;
    for (int i = 0; i < 16; i++) c += (mask[base + i] != 0) ? 1 : 0;
    cnt[tid] = c;
    __syncthreads();
    for (int s = 1; s < 256; s <<= 1) {
      int v = (tid >= s) ? cnt[tid - s] : 0;
      __syncthreads();
      cnt[tid] += v;
      __syncthreads();
    }
    int off = cnt[tid] - c;
    for (int i = 0; i < 16; i++) {
      int idx = base + i;
      if (mask[idx] != 0) list[off++] = idx;
    }
    if (tid == 255) *Mcount = cnt[255];
    return;
  }
  int n = blockIdx.x * 256 + tid;
  int l = labels[n];
  float r[NC];
  float mx = -1e30f, rl = 0.f;
#pragma unroll
  for (int c = 0; c < NC; c++) {
    float v = preds[n * NC + c];
    r[c] = v;
    if (c == l) rl = v;
    mx = fmaxf(mx, v);
  }
  float s = 0.f;
#pragma unroll
  for (int c = 0; c < NC; c++) s += expf(r[c] - mx);
  pos[n] = rl;
  float ce = mx + logf(s) - rl;
  if (mask[n] != 0) atomicAdd(&Ncnt[l], 1);
  __shared__ float red[256];
  red[tid] = ce;
  __syncthreads();
  for (int st = 128; st > 0; st >>= 1) {
    if (tid < st) red[tid] += red[tid + st];
    __syncthreads();
  }
  if (tid == 0) atomicAdd(ceAcc, red[0]);
}

// ---- kernel 3: exact class-pair aggregates (S_inter, E, D) ----------------
// S_inter[i][j] = sum_r cnt_i[r]*cnt_j[r]; E[i][j] = sum over masked,
// non-self-loop r of class j of cnt_i[r]; D[i] = sum deg over masked class i.
__global__ __launch_bounds__(256) void classagg_kernel(
    const u64* __restrict__ bits, const int* __restrict__ deg,
    const int* __restrict__ mask, const int* __restrict__ labels,
    const int* __restrict__ cnt,
    u64* __restrict__ gSI, int* __restrict__ gE, int* __restrict__ gD) {
  __shared__ int eb[100], db[10];
  int tid = threadIdx.x;
  for (int b = tid; b < 100; b += 256) eb[b] = 0;
  if (tid < 10) db[tid] = 0;
  __syncthreads();

  int r = blockIdx.x * 256 + tid;              // 16 blocks x 256 = 4096
  int c[10];
#pragma unroll
  for (int i = 0; i < NC; i++) c[i] = cnt[i * NN + r];

  int sI[55];
  {
    int k = 0;
#pragma unroll
    for (int i = 0; i < NC; i++)
#pragma unroll
      for (int j = i; j < NC; j++) { sI[k] = c[i] * c[j]; k++; }
  }
  // wave reduce the 55 partials
#pragma unroll
  for (int k = 0; k < 55; k++) {
    int v = sI[k];
    for (int d = 1; d < 64; d <<= 1) v += __shfl_xor(v, d);
    sI[k] = v;
  }
  if ((tid & 63) == 0) {
    int k = 0;
    for (int i = 0; i < NC; i++)
      for (int j = i; j < NC; j++) {
        u64 v = (u64)(unsigned int)sI[k];
        if (v) {
          atomicAdd(&gSI[i * NC + j], v);
          if (i != j) atomicAdd(&gSI[j * NC + i], v);
        }
        k++;
      }
  }
  // E and D via LDS bins
  if (mask[r] != 0) {
    int lr = labels[r];
    atomicAdd(&db[lr], deg[r]);
    int selfr = (int)((bits[(size_t)r * NW + (r >> 6)] >> (r & 63)) & 1ULL);
    if (!selfr) {
#pragma unroll
      for (int i = 0; i < NC; i++)
        if (c[i]) atomicAdd(&eb[i * NC + lr], c[i]);
    }
  }
  __syncthreads();
  for (int b = tid; b < 100; b += 256) if (eb[b]) atomicAdd(&gE[b], eb[b]);
  if (tid < 10 && db[tid]) atomicAdd(&gD[tid], db[tid]);
}

// ---- kernel 4: wave-autonomous 32x32 pair tiles, scalar accumulation ------
// No per-pair atomics: weight w[li][lj] = gate*PER/(Ni*Nj) precomputed in the
// prologue from exact integer aggregates. Word-major LDS (one ds_read_b128 =
// 2 rows x 1 word) with unit swizzle sigma(u)=u^((u>>3)&1): all reads land on
// 8 distinct bank-quads (conflict-free). Per-lane register loss accumulator,
// one global atomicAdd per block.
__global__ __launch_bounds__(256, 2) void pair_kernel(
    const u64* __restrict__ bits, const int* __restrict__ deg,
    const float* __restrict__ pos, const float* __restrict__ preds,
    const int* __restrict__ labels, const int* __restrict__ list,
    const int* __restrict__ Mcount, const int* __restrict__ Ncnt,
    const u64* __restrict__ gSI, const int* __restrict__ gE,
    const int* __restrict__ gD, float* __restrict__ gLoss) {
  __shared__ __align__(16) u64 TBW[4][CHW][64];   // 32 KB: word-major, swizzled slots
  __shared__ float predT[4][64][NC];              // 10 KB
  __shared__ int mNode[4][64], mLab[4][64], mDeg[4][64], mSelf[4][64];
  __shared__ float mPos[4][64];
  __shared__ float wLDS[100];
  __shared__ float red[256];

  int tid = threadIdx.x;
  int wv = tid >> 6, lane = tid & 63;

  // prologue: class-pair weights from exact aggregates
  if (tid < 100) {
    int i = tid / NC, j = tid - (tid / NC) * NC;
    s64 SI = (s64)gSI[tid];
    s64 ssub = (s64)gD[i] * (s64)Ncnt[j] - SI - (s64)gE[tid];
    float w = 0.f;
    if (i != j && ssub > 0 && SI > 0) {
      float Ni = fmaxf((float)Ncnt[i], 1.f);
      float Nj = fmaxf((float)Ncnt[j], 1.f);
      w = 0.001f / (Ni * Nj);
    }
    wLDS[tid] = w;
  }
  __syncthreads();

  int M = *Mcount;
  int ntp = (M + BH - 1) / BH;
  int ntiles = (ntp * (ntp + 1)) >> 1;
  int gw = blockIdx.x * 4 + wv;
  int nw = gridDim.x * 4;

  int lp = lane >> 3, lq = lane & 7;          // 8x8 lane grid, 4x4 pairs each
  // read slots: sigma(u) = u ^ ((u>>3)&1), slot = sigma(u)*2 (u64 index)
  int uP0 = 2 * lp, uP1 = 2 * lp + 1;
  int uQ0 = 16 + 2 * lq, uQ1 = 16 + 2 * lq + 1;
  int rdP0 = (uP0 ^ ((uP0 >> 3) & 1)) << 1;
  int rdP1 = (uP1 ^ ((uP1 >> 3) & 1)) << 1;
  int rdQ0 = (uQ0 ^ ((uQ0 >> 3) & 1)) << 1;
  int rdQ1 = (uQ1 ^ ((uQ1 >> 3) & 1)) << 1;
  int uw = lane >> 1;
  int wslot = ((uw ^ ((uw >> 3) & 1)) << 1) + (lane & 1);  // my staging slot

  float lsum = 0.f;

  for (int t = gw; t < ntiles; t += nw) {
    int tp = 0, rem = t;
    while (rem >= ntp - tp) { rem -= ntp - tp; tp++; }
    int tq = tp + rem;
    bool diag = (tp == tq);

    // per-row metadata + preds staging (lane owns row `lane`: 0-31 P, 32-63 Q)
    int mi = (lane < BH) ? (tp * BH + lane) : (tq * BH + (lane - BH));
    int nd = (mi < M) ? list[mi] : -1;
    mNode[wv][lane] = nd;
    mLab[wv][lane]  = (nd >= 0) ? labels[nd] : -1;
    mDeg[wv][lane]  = (nd >= 0) ? deg[nd] : 0;
    mPos[wv][lane]  = (nd >= 0) ? pos[nd] : 0.f;
    mSelf[wv][lane] = (nd >= 0) ? (int)((bits[(size_t)nd * NW + (nd >> 6)] >> (nd & 63)) & 1ULL) : 0;
#pragma unroll
    for (int cc = 0; cc < NC; cc++)
      predT[wv][lane][cc] = (nd >= 0) ? preds[nd * NC + cc] : 0.f;

    const u64* rowp = bits + (size_t)((nd >= 0) ? nd : 0) * NW;
    bool live = (nd >= 0);

    int acc[4][4];
#pragma unroll
    for (int i = 0; i < 4; i++)
#pragma unroll
      for (int j = 0; j < 4; j++) acc[i][j] = 0;

    u64 rwp[4][4], rwq[4][4];   // per-pair adjacency words (loaded at c==3)

    for (int c = 0; c < NCHUNK; c++) {
      // stage chunk c: 16 words of my row into word-major swizzled slots
      ulonglong2 pf[8];
      const u64* src = rowp + c * CHW;
#pragma unroll
      for (int x = 0; x < 8; x++)
        pf[x] = live ? *(const ulonglong2*)(src + (x << 1))
                     : make_ulonglong2(0ULL, 0ULL);
#pragma unroll
      for (int x = 0; x < 8; x++) {
        TBW[wv][2 * x][wslot]     = pf[x].x;
        TBW[wv][2 * x + 1][wslot] = pf[x].y;
      }
      if (c == NCHUNK - 1) {
        // issue epilogue scattered loads; latency hides under last popc chunk
#pragma unroll
        for (int i = 0; i < 4; i++) {
          int pg = mNode[wv][4 * lp + i]; pg = (pg >= 0) ? pg : 0;
#pragma unroll
          for (int j = 0; j < 4; j++) {
            int qg = mNode[wv][BH + 4 * lq + j]; qg = (qg >= 0) ? qg : 0;
            rwp[i][j] = bits[(size_t)pg * NW + (qg >> 6)];
            rwq[i][j] = bits[(size_t)qg * NW + (pg >> 6)];
          }
        }
      }
      // wave-synchronous: drain DS writes before reads (no block barrier)
      asm volatile("s_waitcnt lgkmcnt(0)" ::: "memory");
      __builtin_amdgcn_sched_barrier(0);

#pragma unroll 4
      for (int y = 0; y < CHW; y++) {
        ulonglong2 P0 = *(ulonglong2*)&TBW[wv][y][rdP0];
        ulonglong2 P1 = *(ulonglong2*)&TBW[wv][y][rdP1];
        ulonglong2 Q0 = *(ulonglong2*)&TBW[wv][y][rdQ0];
        ulonglong2 Q1 = *(ulonglong2*)&TBW[wv][y][rdQ1];
        u64 p[4] = {P0.x, P0.y, P1.x, P1.y};
        u64 q[4] = {Q0.x, Q0.y, Q1.x, Q1.y};
#pragma unroll
        for (int i = 0; i < 4; i++)
#pragma unroll
          for (int j = 0; j < 4; j++)
            acc[i][j] += (int)__popcll(p[i] & q[j]);
      }
    }

    // epilogue: pure register/LDS math, scalar weighted accumulation
#pragma unroll
    for (int i = 0; i < 4; i++) {
      int pl = 4 * lp + i;
      int pg = mNode[wv][pl];
      if (pg < 0) continue;
      int li  = mLab[wv][pl];
      int dgp = mDeg[wv][pl];
      int sp  = mSelf[wv][pl];
      float pp = mPos[wv][pl];
#pragma unroll
      for (int j = 0; j < 4; j++) {
        int qr = 4 * lq + j;
        int qg = mNode[wv][BH + qr];
        if (qg < 0) continue;
        int lj = mLab[wv][BH + qr];
        if (li == lj) continue;                 // off-diag class bins only
        if (diag && pl >= qr) continue;         // unordered once on diag tiles
        int inter = acc[i][j];
        int apq = (int)((rwp[i][j] >> (qg & 63)) & 1ULL);
        int aqp = (int)((rwq[i][j] >> (pg & 63)) & 1ULL);
        int sq  = mSelf[wv][BH + qr];
        int sub_f = dgp - inter - (apq & (sq ^ 1));
        int sub_r = mDeg[wv][BH + qr] - inter - (aqp & (sp ^ 1));
        float rden = 1.f / (1.f + S1F * (float)inter);
        float xf = (1.f + S1F * (float)sub_f) * rden;
        float xr = (1.f + S1F * (float)sub_r) * rden;
        float Ef = __expf(predT[wv][BH + qr][li] - pp);
        float Er = __expf(predT[wv][pl][lj] - mPos[wv][BH + qr]);
        float vf = 1.f / (1.f + __expf(xf));    // 1 - sigmoid(x)
        float vr = 1.f / (1.f + __expf(xr));
        lsum += Ef * vf * wLDS[li * NC + lj] + Er * vr * wLDS[lj * NC + li];
      }
    }
    // next tile: wave-order DS makes LDS rewrite safe without barriers
  }

  red[tid] = lsum;
  __syncthreads();
  for (int s = 128; s > 0; s >>= 1) {
    if (tid < s) red[tid] += red[tid + s];
    __syncthreads();
  }
  if (tid == 0 && red[0] != 0.f) atomicAdd(gLoss, red[0]);
}

// ---- kernel 5: final assembly ---------------------------------------------
__global__ void fin_kernel(const float* __restrict__ ceAcc,
                           const float* __restrict__ gLoss,
                           float* __restrict__ out) {
  out[0] = ceAcc[0] / (float)NN + gLoss[0];
}

// ---- launch ---------------------------------------------------------------
extern "C" void kernel_launch(void* const* d_in, const int* in_sizes, int n_in,
                              void* d_out, int out_size, void* d_ws, size_t ws_size,
                              hipStream_t stream) {
  const float* preds  = (const float*)d_in[0];
  const int*   labels = (const int*)d_in[1];
  const int*   mask   = (const int*)d_in[2];
  const int*   adj    = (const int*)d_in[3];

  char* ws = (char*)d_ws;
  u64*   bits  = (u64*)(ws + OFF_BITS);
  int*   deg   = (int*)(ws + OFF_DEG);
  float* pos   = (float*)(ws + OFF_POS);
  int*   list  = (int*)(ws + OFF_LIST);
  char*  accb  = ws + OFF_ACC;
  float* ceAcc = (float*)(accb + A_CE);
  float* gLoss = (float*)(accb + A_LOSS);
  int*   Mcnt  = (int*)(accb + A_MCNT);
  int*   Ncnt  = (int*)(accb + A_NCNT);
  int*   gD    = (int*)(accb + A_GD);
  int*   gE    = (int*)(accb + A_GE);
  u64*   gSI   = (u64*)(accb + A_GSI);
  int*   cnt   = (int*)(ws + OFF_CNT);

  // zero acc strip + cnt table (contiguous: 1536 + 163840 bytes)
  hipMemsetAsync(ws + OFF_ACC, 0, 1536 + 163840, stream);

  hipLaunchKernelGGL(pack_bits_kernel, dim3(NN), dim3(256), 0, stream,
                     adj, bits, deg, cnt, labels, mask);
  hipLaunchKernelGGL(node_compact_kernel, dim3(17), dim3(256), 0, stream,
                     preds, labels, mask, pos, Ncnt, ceAcc, list, Mcnt);
  hipLaunchKernelGGL(classagg_kernel, dim3(16), dim3(256), 0, stream,
                     bits, deg, mask, labels, cnt, gSI, gE, gD);
  // M=2048 -> ntp=64 -> 2080 tiles; 520 blocks x 4 waves = 2080 (1/wave);
  // wave-stride covers larger M (8256 tiles @ M=4096 -> 4/wave).
  hipLaunchKernelGGL(pair_kernel, dim3(520), dim3(256), 0, stream,
                     bits, deg, pos, preds, labels, list, Mcnt, Ncnt,
                     gSI, gE, gD, gLoss);
  hipLaunchKernelGGL(fin_kernel, dim3(1), dim3(1), 0, stream,
                     ceAcc, gLoss, (float*)d_out);
}